// Round 7
// baseline (2996.786 us; speedup 1.0000x reference)
//
#include <hip/hip_runtime.h>
#include <math.h>

#define NRW 131072
#define W   128
#define K   1024
#define C   4
#define NT  256   // one row per thread

__device__ __forceinline__ float fmulr(float a, float b){ return __fmul_rn(a,b); }
__device__ __forceinline__ float faddr(float a, float b){ return __fadd_rn(a,b); }
__device__ __forceinline__ float fsubr(float a, float b){ return __fsub_rn(a,b); }

// XLA:CPU reduce semantics: scalar sequential ascending, init 0:
// acc = fl(acc + fl(x*x))
__device__ __forceinline__ float seq_sumsq_reg(const float* p) {
    float a = 0.f;
    #pragma unroll
    for (int w = 0; w < W; ++w) a = faddr(a, fmulr(p[w], p[w]));
    return a;
}

__device__ float seq_sumsq_glb(const float* __restrict__ p) {
    float a = 0.f;
    for (int w = 0; w < W; ++w) { const float v = p[w]; a = faddr(a, fmulr(v, v)); }
    return a;
}

__global__ __launch_bounds__(NT, 2) void rqxla_kernel(
    const float* __restrict__ X, const float* __restrict__ CB,
    float* __restrict__ out)
{
    __shared__ float c2s[K];   // per-stage ||c||^2, XLA sequential-reduce bits

    const int tid = threadIdx.x;
    const int n   = blockIdx.x * NT + tid;

    // residual row lives entirely in VGPRs
    float R[W];
    {
        const float* xr = X + (size_t)n * W;
        #pragma unroll
        for (int q = 0; q < W / 4; ++q) {
            const float4 v = *(const float4*)(xr + q * 4);
            R[q * 4 + 0] = v.x; R[q * 4 + 1] = v.y;
            R[q * 4 + 2] = v.z; R[q * 4 + 3] = v.w;
        }
    }

    for (int st = 0; st < C; ++st) {
        const float* cb = CB + (size_t)st * K * W;

        __syncthreads();   // previous stage finished reading c2s
        for (int k = tid; k < K; k += NT)
            c2s[k] = seq_sumsq_glb(cb + (size_t)k * W);

        const float r2 = seq_sumsq_reg(R);
        __syncthreads();   // c2s ready

        float bd = 3.4e38f;
        int   bk = 0;

        // dot = single-accumulator FMA chain ascending w (Eigen/oneDNN gemm bits).
        // k uniform across the wave -> codebook row broadcast (SMEM/L1).
        for (int k = 0; k < K; k += 2) {
            const float* c0 = cb + (size_t)k * W;
            const float* c1 = c0 + W;
            float a0 = 0.f, a1 = 0.f;
            #pragma unroll
            for (int w = 0; w < W; ++w) {
                a0 = __fmaf_rn(R[w], c0[w], a0);
                a1 = __fmaf_rn(R[w], c1[w], a1);
            }
            // d2 = fl( fl(r2 - 2*dot) + c2 ); 2*dot exact
            const float d0 = faddr(fsubr(r2, faddr(a0, a0)), c2s[k]);
            const float d1 = faddr(fsubr(r2, faddr(a1, a1)), c2s[k + 1]);
            if (d0 < bd) { bd = d0; bk = k; }          // ascending, strict <
            if (d1 < bd) { bd = d1; bk = k + 1; }      // = first-min ties
        }

        out[(size_t)st * NRW + n] = (float)bk;                                   // idx [C,N]
        out[(size_t)C * NRW + (size_t)n * C + st] = __fsqrt_rn(fmaxf(bd, 0.f));  // dists [N,C]

        if (st < C - 1) {
            const float* cw = cb + (size_t)bk * W;     // per-lane gather
            #pragma unroll
            for (int q = 0; q < W / 4; ++q) {
                const float4 v = *(const float4*)(cw + q * 4);
                R[q * 4 + 0] = fsubr(R[q * 4 + 0], v.x);
                R[q * 4 + 1] = fsubr(R[q * 4 + 1], v.y);
                R[q * 4 + 2] = fsubr(R[q * 4 + 2], v.z);
                R[q * 4 + 3] = fsubr(R[q * 4 + 3], v.w);
            }
        }
    }
}

extern "C" void kernel_launch(void* const* d_in, const int* in_sizes, int n_in,
                              void* d_out, int out_size, void* d_ws, size_t ws_size,
                              hipStream_t stream) {
    const float* X  = (const float*)d_in[0];
    const float* CB = (const float*)d_in[1];
    float* out = (float*)d_out;
    rqxla_kernel<<<dim3(NRW / NT), NT, 0, stream>>>(X, CB, out);
}

// Round 8
// 2080.312 us; speedup vs baseline: 1.4405x; 1.4405x over previous
//
#include <hip/hip_runtime.h>
#include <math.h>

#define NRW 131072
#define W   128
#define K   1024
#define C   4
#define BN  64     // rows per block
#define BK  64     // k per tile
#define NT  256

__device__ __forceinline__ float fmulr(float a, float b){ return __fmul_rn(a,b); }
__device__ __forceinline__ float faddr(float a, float b){ return __fadd_rn(a,b); }
__device__ __forceinline__ float fsubr(float a, float b){ return __fsub_rn(a,b); }

// XLA:CPU reduce bits: acc = fl(acc + fl(v*v)), ascending, init 0
__device__ float seq_sumsq_glb(const float* __restrict__ p) {
    float a = 0.f;
    for (int w = 0; w < W; ++w) { const float v = p[w]; a = faddr(a, fmulr(v, v)); }
    return a;
}

__global__ __launch_bounds__(256) void c2_kernel(const float* __restrict__ CB,
                                                 float* __restrict__ c2g) {
    const int kg = blockIdx.x * 256 + threadIdx.x;   // 0 .. C*K-1
    if (kg < C * K) c2g[kg] = seq_sumsq_glb(CB + (size_t)kg * W);
}

__global__ __launch_bounds__(NT, 2) void rqgemm_kernel(
    const float* __restrict__ X, const float* __restrict__ CB,
    const float* __restrict__ c2g, float* __restrict__ out)
{
    __shared__ float4 Ct4[BK][32];                        // [k][w4 ^ ((k>>2)&15)]
    __shared__ __attribute__((aligned(16))) float Rt[W][BN + 4];  // transposed residual
    __shared__ float c2l[K];
    __shared__ float r2s[BN];
    __shared__ int   widx[BN];

    const int tid = threadIdx.x;
    const int n0  = blockIdx.x * BN;
    const int tj  = tid & 15;
    const int ti  = tid >> 4;
    const int i0  = ti * 4;      // 4 rows per thread
    const int j0  = tj * 4;      // 4 ks per thread within tile

    // ---- initial residual = X (transposed into LDS) ----
    for (int e = tid; e < BN * 32; e += NT) {
        const int row = e >> 5, q = e & 31;
        const float4 v = *(const float4*)(X + (size_t)(n0 + row) * W + q * 4);
        Rt[q * 4 + 0][row] = v.x;
        Rt[q * 4 + 1][row] = v.y;
        Rt[q * 4 + 2][row] = v.z;
        Rt[q * 4 + 3][row] = v.w;
    }

    for (int st = 0; st < C; ++st) {
        const float*  cb  = CB + (size_t)st * K * W;
        const float4* cb4 = (const float4*)cb;

        __syncthreads();   // prior stage fully done (c2l/r2s free, Rt updated)
        for (int kk = tid; kk < K; kk += NT) c2l[kk] = c2g[st * K + kk];
        if (tid < BN) {    // r2: sequential chain ascending w (XLA bits)
            float a = 0.f;
            for (int w = 0; w < W; ++w) { const float v = Rt[w][tid]; a = faddr(a, fmulr(v, v)); }
            r2s[tid] = a;
        }
        __syncthreads();   // c2l, r2s ready

        float bd[4]; int bk[4];
        #pragma unroll
        for (int r = 0; r < 4; ++r) { bd[r] = 3.4e38f; bk[r] = 0x7fffffff; }

        for (int kt = 0; kt < K / BK; ++kt) {
            const int kbase = kt * BK;

            // stage codebook tile: coalesced global float4, swizzled LDS column
            for (int f = tid; f < BK * 32; f += NT) {
                const int kl = f >> 5, w4 = f & 31;
                Ct4[kl][w4 ^ ((kl >> 2) & 15)] = cb4[(size_t)(kbase + kl) * 32 + w4];
            }
            __syncthreads();

            float acc[4][4];
            #pragma unroll
            for (int r = 0; r < 4; ++r)
                #pragma unroll
                for (int c = 0; c < 4; ++c) acc[r][c] = 0.f;

            #pragma unroll 2
            for (int qw = 0; qw < 32; ++qw) {
                float ca[4][4], ra[4][4];
                #pragma unroll
                for (int c = 0; c < 4; ++c) {
                    const float4 v = Ct4[j0 + c][qw ^ tj];   // ((j0+c)>>2)&15 == tj
                    ca[c][0] = v.x; ca[c][1] = v.y; ca[c][2] = v.z; ca[c][3] = v.w;
                }
                #pragma unroll
                for (int q = 0; q < 4; ++q) {
                    const float4 v = *(const float4*)(&Rt[qw * 4 + q][i0]);
                    ra[q][0] = v.x; ra[q][1] = v.y; ra[q][2] = v.z; ra[q][3] = v.w;
                }
                // w = qw*4 + q ascending per accumulator chain (XLA gemm bits)
                #pragma unroll
                for (int q = 0; q < 4; ++q)
                    #pragma unroll
                    for (int r = 0; r < 4; ++r)
                        #pragma unroll
                        for (int c = 0; c < 4; ++c)
                            acc[r][c] = __fmaf_rn(ra[q][r], ca[c][q], acc[r][c]);
            }

            // d2 = fl(fl(r2 - 2*dot) + c2); per-thread ascending-k argmin, strict <
            #pragma unroll
            for (int c = 0; c < 4; ++c) {
                const int   kk  = kbase + j0 + c;
                const float cc2 = c2l[kk];
                #pragma unroll
                for (int r = 0; r < 4; ++r) {
                    const float d2 = faddr(fsubr(r2s[i0 + r], faddr(acc[r][c], acc[r][c])), cc2);
                    if (d2 < bd[r]) { bd[r] = d2; bk[r] = kk; }
                }
            }
            __syncthreads();   // Ct consumed; safe to restage
        }

        // lexicographic (d2,k) merge across the 16 tj-lanes (same rows) -> global first-min
        #pragma unroll
        for (int m = 8; m >= 1; m >>= 1) {
            #pragma unroll
            for (int r = 0; r < 4; ++r) {
                const float od = __shfl_xor(bd[r], m, 16);
                const int   ok = __shfl_xor(bk[r], m, 16);
                if (od < bd[r] || (od == bd[r] && ok < bk[r])) { bd[r] = od; bk[r] = ok; }
            }
        }

        if (tj == 0) {
            #pragma unroll
            for (int r = 0; r < 4; ++r) {
                const int row = i0 + r;
                widx[row] = bk[r];
                out[(size_t)st * NRW + (n0 + row)] = (float)bk[r];
                out[(size_t)C * NRW + (size_t)(n0 + row) * C + st] =
                    __fsqrt_rn(fmaxf(bd[r], 0.f));
            }
        }
        __syncthreads();   // widx ready; all GEMM reads of Rt done

        if (st < C - 1) {
            // residual -= cb[idx]: coalesced global read, elementwise f32 (bit-exact)
            for (int e = tid; e < BN * W; e += NT) {
                const int row = e >> 7, w = e & 127;
                const float v = cb[(size_t)widx[row] * W + w];
                Rt[w][row] = fsubr(Rt[w][row], v);
            }
        }
    }
}

extern "C" void kernel_launch(void* const* d_in, const int* in_sizes, int n_in,
                              void* d_out, int out_size, void* d_ws, size_t ws_size,
                              hipStream_t stream) {
    const float* X  = (const float*)d_in[0];
    const float* CB = (const float*)d_in[1];
    float* out = (float*)d_out;
    float* c2g = (float*)d_ws;   // C*K floats = 16 KB scratch

    c2_kernel<<<dim3((C * K + 255) / 256), 256, 0, stream>>>(CB, c2g);
    rqgemm_kernel<<<dim3(NRW / BN), NT, 0, stream>>>(X, CB, c2g, out);
}

// Round 9
// 912.627 us; speedup vs baseline: 3.2837x; 2.2795x over previous
//
#include <hip/hip_runtime.h>
#include <math.h>

#define NRW 131072
#define W   128
#define K   1024
#define C   4
#define BN  128
#define NT  512

typedef _Float16 f16;
typedef _Float16 f16x8 __attribute__((ext_vector_type(8)));
typedef float    f32x4 __attribute__((ext_vector_type(4)));

__device__ __forceinline__ float fmulr(float a, float b){ return __fmul_rn(a,b); }
__device__ __forceinline__ float faddr(float a, float b){ return __fadd_rn(a,b); }
__device__ __forceinline__ float fsubr(float a, float b){ return __fsub_rn(a,b); }

// XLA:CPU reduce bits: acc = fl(acc + fl(v*v)), ascending w, init 0
__device__ float seq_sumsq_glb(const float* __restrict__ p){
    float a = 0.f;
    for (int w = 0; w < W; ++w){ const float v = p[w]; a = faddr(a, fmulr(v, v)); }
    return a;
}

__global__ __launch_bounds__(256) void c2_kernel(const float* __restrict__ CB,
                                                 float* __restrict__ c2g){
    const int kg = blockIdx.x * 256 + threadIdx.x;
    if (kg < C * K) c2g[kg] = seq_sumsq_glb(CB + (size_t)kg * W);
}

// Split codebook to f16 hi/lo, FRAGMENT-MAJOR for mfma_f32_16x16x32_f16 B-operand:
// element (s,k,w): kb=k>>4, q=w>>5, lane=((w>>3)&3)*16 + (k&15), j=w&7
// off = (((s*64+kb)*4+q)*64 + lane)*8 + j   (f16 units; tile of 4 kb = 16KB contiguous)
__global__ __launch_bounds__(256) void split_kernel(const float* __restrict__ CB,
                                                    f16* __restrict__ Bh, f16* __restrict__ Bl){
    const int g  = blockIdx.x * 256 + threadIdx.x;     // 65536 total
    const int s  = g >> 14, k = (g >> 4) & 1023, w8 = g & 15;
    const float* src = CB + ((size_t)(s * K + k)) * W + w8 * 8;
    const size_t off = ((((size_t)(s * 64 + (k >> 4)) * 4 + (w8 >> 2)) * 64)
                        + ((w8 & 3) * 16 + (k & 15))) * 8;
    f16x8 hv, lv;
    #pragma unroll
    for (int j = 0; j < 8; ++j){
        const float x = src[j];
        const f16 h = (f16)x;
        hv[j] = h;
        lv[j] = (f16)(x - (float)h);
    }
    *(f16x8*)(Bh + off) = hv;
    *(f16x8*)(Bl + off) = lv;
}

#define GLD_LDS(gp, lp) __builtin_amdgcn_global_load_lds( \
    (const __attribute__((address_space(1))) void*)(gp),  \
    (__attribute__((address_space(3))) void*)(lp), 16, 0, 0)

__global__ __launch_bounds__(NT, 1) void rqmfma_kernel(
    const float* __restrict__ X, const float* __restrict__ CB,
    const float* __restrict__ c2g, const f16* __restrict__ BhG,
    const f16* __restrict__ BlG, float* __restrict__ out)
{
    __shared__ __attribute__((aligned(16))) float Rt[BN][W + 4];   // stride 132
    __shared__ __attribute__((aligned(16))) f16 BtH[2][8192];      // 16KB tile (4 kb) x2 buf
    __shared__ __attribute__((aligned(16))) f16 BtL[2][8192];
    __shared__ float c2l[K];
    __shared__ float r2s[BN];
    __shared__ int   cand[BN][2];
    __shared__ float dve[BN][2];
    __shared__ int   widx[BN];

    const int tid = threadIdx.x;
    const int wv  = tid >> 6;     // wave 0..7 -> rows wv*16..wv*16+15
    const int ln  = tid & 63;
    const int n0  = blockIdx.x * BN;

    // init residual = X
    for (int f = tid; f < BN * 32; f += NT){
        const int row = f >> 5, q = f & 31;
        *(float4*)(&Rt[row][q * 4]) = *(const float4*)(X + (size_t)(n0 + row) * W + q * 4);
    }

    for (int st = 0; st < C; ++st){
        const float* cb = CB + (size_t)st * K * W;

        __syncthreads();                       // residual ready
        if (tid < BN){                         // XLA r2 chain (exact bits)
            float a = 0.f;
            for (int w = 0; w < W; ++w){ const float v = Rt[tid][w]; a = faddr(a, fmulr(v, v)); }
            r2s[tid] = a;
        }
        for (int k2 = tid; k2 < K; k2 += NT) c2l[k2] = c2g[st * K + k2];
        __syncthreads();                       // r2s, c2l ready

        // A fragments (16 rows of this wave), f16 split, all 4 k-steps
        f16x8 ah[4], al[4];
        {
            const int r  = wv * 16 + (ln & 15);
            const int wb = (ln >> 4) * 8;
            #pragma unroll
            for (int q = 0; q < 4; ++q){
                const float* p = &Rt[r][q * 32 + wb];
                f16x8 h, l;
                #pragma unroll
                for (int j = 0; j < 8; ++j){
                    const float x = p[j];
                    const f16 hh = (f16)x;
                    h[j] = hh;
                    l[j] = (f16)(x - (float)hh);
                }
                ah[q] = h; al[q] = l;
            }
        }
        float r2v[4];
        #pragma unroll
        for (int rg = 0; rg < 4; ++rg) r2v[rg] = r2s[wv * 16 + (ln >> 4) * 4 + rg];

        float bd1[4], bd2[4]; int bk1[4], bk2[4];
        #pragma unroll
        for (int rg = 0; rg < 4; ++rg){ bd1[rg] = 3.4e38f; bd2[rg] = 3.4e38f; bk1[rg] = 0; bk2[rg] = 1; }

        // stage tile 0 (async global->LDS), tileByte(t) = st*256KB + t*16KB
        {
            const size_t gb = (size_t)st * 262144;
            const int ci = wv * 128;
            #pragma unroll
            for (int r = 0; r < 2; ++r){
                const int idx = ci + r * 64;
                GLD_LDS((const char*)BhG + gb + (size_t)(idx + ln) * 16, &BtH[0][idx * 8]);
                GLD_LDS((const char*)BlG + gb + (size_t)(idx + ln) * 16, &BtL[0][idx * 8]);
            }
        }
        __syncthreads();   // vmcnt drained -> buf0 ready

        for (int t = 0; t < 16; ++t){
            const int cur = t & 1;
            if (t < 15){   // prefetch next tile into other buffer
                const size_t gb = (size_t)st * 262144 + (size_t)(t + 1) * 16384;
                const int ci = wv * 128;
                #pragma unroll
                for (int r = 0; r < 2; ++r){
                    const int idx = ci + r * 64;
                    GLD_LDS((const char*)BhG + gb + (size_t)(idx + ln) * 16, &BtH[cur ^ 1][idx * 8]);
                    GLD_LDS((const char*)BlG + gb + (size_t)(idx + ln) * 16, &BtL[cur ^ 1][idx * 8]);
                }
            }
            #pragma unroll
            for (int c = 0; c < 4; ++c){
                f16x8 bh0 = *(const f16x8*)(&BtH[cur][((c * 4 + 0) * 64 + ln) * 8]);
                f16x8 bh1 = *(const f16x8*)(&BtH[cur][((c * 4 + 1) * 64 + ln) * 8]);
                f16x8 bh2 = *(const f16x8*)(&BtH[cur][((c * 4 + 2) * 64 + ln) * 8]);
                f16x8 bh3 = *(const f16x8*)(&BtH[cur][((c * 4 + 3) * 64 + ln) * 8]);
                f16x8 bl0 = *(const f16x8*)(&BtL[cur][((c * 4 + 0) * 64 + ln) * 8]);
                f16x8 bl1 = *(const f16x8*)(&BtL[cur][((c * 4 + 1) * 64 + ln) * 8]);
                f16x8 bl2 = *(const f16x8*)(&BtL[cur][((c * 4 + 2) * 64 + ln) * 8]);
                f16x8 bl3 = *(const f16x8*)(&BtL[cur][((c * 4 + 3) * 64 + ln) * 8]);
                f32x4 acc = {0.f, 0.f, 0.f, 0.f};
                acc = __builtin_amdgcn_mfma_f32_16x16x32_f16(ah[0], bh0, acc, 0, 0, 0);
                acc = __builtin_amdgcn_mfma_f32_16x16x32_f16(ah[1], bh1, acc, 0, 0, 0);
                acc = __builtin_amdgcn_mfma_f32_16x16x32_f16(ah[2], bh2, acc, 0, 0, 0);
                acc = __builtin_amdgcn_mfma_f32_16x16x32_f16(ah[3], bh3, acc, 0, 0, 0);
                acc = __builtin_amdgcn_mfma_f32_16x16x32_f16(ah[0], bl0, acc, 0, 0, 0);
                acc = __builtin_amdgcn_mfma_f32_16x16x32_f16(ah[1], bl1, acc, 0, 0, 0);
                acc = __builtin_amdgcn_mfma_f32_16x16x32_f16(ah[2], bl2, acc, 0, 0, 0);
                acc = __builtin_amdgcn_mfma_f32_16x16x32_f16(ah[3], bl3, acc, 0, 0, 0);
                acc = __builtin_amdgcn_mfma_f32_16x16x32_f16(al[0], bh0, acc, 0, 0, 0);
                acc = __builtin_amdgcn_mfma_f32_16x16x32_f16(al[1], bh1, acc, 0, 0, 0);
                acc = __builtin_amdgcn_mfma_f32_16x16x32_f16(al[2], bh2, acc, 0, 0, 0);
                acc = __builtin_amdgcn_mfma_f32_16x16x32_f16(al[3], bh3, acc, 0, 0, 0);

                const int   kcur = (t * 4 + c) * 16 + (ln & 15);
                const float c2v  = c2l[kcur];
                #pragma unroll
                for (int rg = 0; rg < 4; ++rg){
                    const float d2a = fmaf(-2.f, acc[rg], r2v[rg] + c2v);
                    if (d2a < bd1[rg]) { bd2[rg] = bd1[rg]; bk2[rg] = bk1[rg]; bd1[rg] = d2a; bk1[rg] = kcur; }
                    else if (d2a < bd2[rg]) { bd2[rg] = d2a; bk2[rg] = kcur; }
                }
            }
            __syncthreads();   // next tile landed; cur buffer free
        }

        // merge top-2 across the 16 column lanes (lexicographic)
        #pragma unroll
        for (int m = 8; m >= 1; m >>= 1){
            #pragma unroll
            for (int rg = 0; rg < 4; ++rg){
                const float o1 = __shfl_xor(bd1[rg], m, 16); const int p1 = __shfl_xor(bk1[rg], m, 16);
                const float o2 = __shfl_xor(bd2[rg], m, 16); const int p2 = __shfl_xor(bk2[rg], m, 16);
                float n1d, n2d; int n1k, n2k;
                const bool lt1 = (o1 < bd1[rg]) || (o1 == bd1[rg] && p1 < bk1[rg]);
                if (lt1){
                    n1d = o1; n1k = p1;
                    const bool lt2 = (bd1[rg] < o2) || (bd1[rg] == o2 && bk1[rg] < p2);
                    if (lt2){ n2d = bd1[rg]; n2k = bk1[rg]; } else { n2d = o2; n2k = p2; }
                } else {
                    n1d = bd1[rg]; n1k = bk1[rg];
                    const bool lt2 = (o1 < bd2[rg]) || (o1 == bd2[rg] && p1 < bk2[rg]);
                    if (lt2){ n2d = o1; n2k = p1; } else { n2d = bd2[rg]; n2k = bk2[rg]; }
                }
                bd1[rg] = n1d; bk1[rg] = n1k; bd2[rg] = n2d; bk2[rg] = n2k;
            }
        }
        if ((ln & 15) == 0){
            #pragma unroll
            for (int rg = 0; rg < 4; ++rg){
                const int row = wv * 16 + (ln >> 4) * 4 + rg;
                cand[row][0] = bk1[rg];
                cand[row][1] = bk2[rg];
            }
        }
        __syncthreads();

        // exact XLA-bits re-evaluation of both candidates
        if (tid < 2 * BN){
            const int row = tid >> 1, cd = tid & 1;
            const int k   = cand[row][cd];
            const float* cw = cb + (size_t)k * W;
            float dot = 0.f;
            for (int w = 0; w < W; ++w) dot = __fmaf_rn(Rt[row][w], cw[w], dot);
            dve[row][cd] = faddr(fsubr(r2s[row], faddr(dot, dot)), c2l[k]);
        }
        __syncthreads();

        if (tid < BN){
            const float a0 = dve[tid][0], a1 = dve[tid][1];
            const int   i0 = cand[tid][0], i1 = cand[tid][1];
            int wi; float wd;
            if (a1 < a0 || (a1 == a0 && i1 < i0)){ wi = i1; wd = a1; } else { wi = i0; wd = a0; }
            widx[tid] = wi;
            out[(size_t)st * NRW + (n0 + tid)] = (float)wi;
            out[(size_t)C * NRW + (size_t)(n0 + tid) * C + st] = __fsqrt_rn(fmaxf(wd, 0.f));
        }
        __syncthreads();

        if (st < C - 1){
            const float4* cb4 = (const float4*)cb;
            for (int f = tid; f < BN * 32; f += NT){
                const int row = f >> 5, q = f & 31;
                const float4 v = cb4[(size_t)widx[row] * 32 + q];
                float* rp = &Rt[row][q * 4];
                rp[0] = fsubr(rp[0], v.x); rp[1] = fsubr(rp[1], v.y);
                rp[2] = fsubr(rp[2], v.z); rp[3] = fsubr(rp[3], v.w);
            }
        }
    }
}

extern "C" void kernel_launch(void* const* d_in, const int* in_sizes, int n_in,
                              void* d_out, int out_size, void* d_ws, size_t ws_size,
                              hipStream_t stream) {
    const float* X  = (const float*)d_in[0];
    const float* CB = (const float*)d_in[1];
    float* out = (float*)d_out;

    float* c2g = (float*)d_ws;                              // 16 KB
    f16*   Bh  = (f16*)((char*)d_ws + 16384);               // 1 MB
    f16*   Bl  = (f16*)((char*)d_ws + 16384 + 1048576);     // 1 MB

    c2_kernel<<<dim3((C * K + 255) / 256), 256, 0, stream>>>(CB, c2g);
    split_kernel<<<dim3(C * K * 16 / 256), 256, 0, stream>>>(CB, Bh, Bl);
    rqmfma_kernel<<<dim3(NRW / BN), NT, 0, stream>>>(X, CB, c2g, Bh, Bl, out);
}

// Round 10
// 498.913 us; speedup vs baseline: 6.0066x; 1.8292x over previous
//
#include <hip/hip_runtime.h>
#include <math.h>

#define NRW 131072
#define W   128
#define K   1024
#define C   4
#define BN  128
#define NT  512

typedef _Float16 f16;
typedef _Float16 f16x8 __attribute__((ext_vector_type(8)));
typedef float    f32x4 __attribute__((ext_vector_type(4)));

__device__ __forceinline__ float fmulr(float a, float b){ return __fmul_rn(a,b); }
__device__ __forceinline__ float faddr(float a, float b){ return __fadd_rn(a,b); }
__device__ __forceinline__ float fsubr(float a, float b){ return __fsub_rn(a,b); }
__device__ __forceinline__ unsigned umin(unsigned a, unsigned b){ return a < b ? a : b; }
__device__ __forceinline__ unsigned umax(unsigned a, unsigned b){ return a > b ? a : b; }

// XLA:CPU reduce bits: acc = fl(acc + fl(v*v)), ascending, init 0
__device__ float seq_sumsq_glb(const float* __restrict__ p){
    float a = 0.f;
    for (int w = 0; w < W; ++w){ const float v = p[w]; a = faddr(a, fmulr(v, v)); }
    return a;
}

__global__ __launch_bounds__(256) void c2_kernel(const float* __restrict__ CB,
                                                 float* __restrict__ c2g){
    const int kg = blockIdx.x * 256 + threadIdx.x;
    if (kg < C * K) c2g[kg] = seq_sumsq_glb(CB + (size_t)kg * W);
}

// f16 hi/lo split, fragment-major B layout for mfma_f32_16x16x32_f16 (verified R9):
// off = (((s*64 + (k>>4))*4 + q)*64 + ((w8&3)*16 + (k&15)))*8, q = w>>5, w8 = w>>3
__global__ __launch_bounds__(256) void split_kernel(const float* __restrict__ CB,
                                                    f16* __restrict__ Bh, f16* __restrict__ Bl){
    const int g  = blockIdx.x * 256 + threadIdx.x;     // 65536 total
    const int s  = g >> 14, k = (g >> 4) & 1023, w8 = g & 15;
    const float* src = CB + ((size_t)(s * K + k)) * W + w8 * 8;
    const size_t off = ((((size_t)(s * 64 + (k >> 4)) * 4 + (w8 >> 2)) * 64)
                        + ((w8 & 3) * 16 + (k & 15))) * 8;
    f16x8 hv, lv;
    #pragma unroll
    for (int j = 0; j < 8; ++j){
        const float x = src[j];
        const f16 h = (f16)x;
        hv[j] = h;
        lv[j] = (f16)(x - (float)h);
    }
    *(f16x8*)(Bh + off) = hv;
    *(f16x8*)(Bl + off) = lv;
}

#define DPP_TOP2(p1, p2, RCTL)                                                          \
    {                                                                                   \
        const unsigned q1 = (unsigned)__builtin_amdgcn_update_dpp((int)(p1), (int)(p1), \
                                                                  (RCTL), 0xF, 0xF, false); \
        const unsigned q2 = (unsigned)__builtin_amdgcn_update_dpp((int)(p2), (int)(p2), \
                                                                  (RCTL), 0xF, 0xF, false); \
        const unsigned t = umax(p1, q1);                                                \
        p1 = umin(p1, q1);                                                              \
        p2 = umin(t, umin(p2, q2));                                                     \
    }

__global__ __launch_bounds__(NT, 2) void rq10_kernel(
    const float* __restrict__ X, const float* __restrict__ CB,
    const float* __restrict__ c2g, const f16* __restrict__ BhG,
    const f16* __restrict__ BlG, float* __restrict__ out)
{
    __shared__ float Rt[BN][W + 1];                 // 66048 B, stride 129 (odd: chain phases conflict-free)
    __shared__ __attribute__((aligned(16))) f16 AH[8 * 4 * 64 * 8];   // 32 KB fragment-major A hi
    __shared__ __attribute__((aligned(16))) f16 AL[8 * 4 * 64 * 8];   // 32 KB A lo
    __shared__ unsigned long long mslot[BN * 17];   // 17 KB, row stride 17 (bank spread); [row][wv*2+half]
    __shared__ int   cand[BN][2];
    __shared__ float dve[BN][2];
    __shared__ int   widx[BN];

    const int tid = threadIdx.x;
    const int wv  = tid >> 6;      // wave 0..7 = k-slice
    const int ln  = tid & 63;
    const int col = ln & 15;
    const int n0  = blockIdx.x * BN;

    // ---- initial residual = X (scalar LDS stores; stride 129) ----
    for (int e = tid; e < BN * 32; e += NT){
        const int row = e >> 5, q = e & 31;
        const float4 v = *(const float4*)(X + (size_t)(n0 + row) * W + q * 4);
        float* rp = &Rt[row][q * 4];
        rp[0] = v.x; rp[1] = v.y; rp[2] = v.z; rp[3] = v.w;
    }

    for (int st = 0; st < C; ++st){
        const float*  cb  = CB + (size_t)st * K * W;
        const float4* cb4 = (const float4*)cb;

        __syncthreads();   // Rt stable (fill or update)

        // ---- extract A fragments -> f16 hi/lo LDS (approx; any bits ok); init mslot ----
        for (int s = tid; s < 2048; s += NT){
            const int frag = s >> 6, lns = s & 63;
            const int row = ((frag >> 2) << 4) + (lns & 15);
            const int w0  = ((frag & 3) << 5) + ((lns >> 4) << 3);
            const float* rp = &Rt[row][w0];
            f16x8 h, l;
            #pragma unroll
            for (int j = 0; j < 8; ++j){
                const float x = rp[j];
                const f16 hh = (f16)x;
                h[j] = hh;
                l[j] = (f16)(x - (float)hh);
            }
            *(f16x8*)&AH[s * 8] = h;
            *(f16x8*)&AL[s * 8] = l;
        }
        for (int s = tid; s < BN * 17; s += NT) mslot[s] = ~0ull;
        __syncthreads();   // AH/AL + mslot ready

        // ---- MFMA scan: wave wv owns k in [wv*128, wv*128+128), two 64-k halves ----
        const f16* BhS = BhG + (size_t)st * (64 * 4 * 64 * 8);
        const f16* BlS = BlG + (size_t)st * (64 * 4 * 64 * 8);

        #pragma unroll 1
        for (int half = 0; half < 2; ++half){
            const int KB0 = wv * 8 + half * 4;
            f16x8 bh[4][4], bl[4][4];
            #pragma unroll
            for (int kb = 0; kb < 4; ++kb)
                #pragma unroll
                for (int q = 0; q < 4; ++q){
                    const size_t fo = ((size_t)((KB0 + kb) * 4 + q) * 64 + ln) * 8;
                    bh[kb][q] = *(const f16x8*)(BhS + fo);
                    bl[kb][q] = *(const f16x8*)(BlS + fo);
                }
            float c2r[4]; unsigned kreg[4];
            #pragma unroll
            for (int kb = 0; kb < 4; ++kb){
                kreg[kb] = (unsigned)(((KB0 + kb) << 4) + col);
                c2r[kb]  = c2g[st * K + (int)kreg[kb]];
            }

            #pragma unroll 1
            for (int rb = 0; rb < 8; ++rb){
                f16x8 ah[4], al[4];
                #pragma unroll
                for (int q = 0; q < 4; ++q){
                    ah[q] = *(const f16x8*)&AH[(((rb * 4 + q) * 64) + ln) * 8];
                    al[q] = *(const f16x8*)&AL[(((rb * 4 + q) * 64) + ln) * 8];
                }
                f32x4 acc[4];
                #pragma unroll
                for (int kb = 0; kb < 4; ++kb) acc[kb] = (f32x4){0.f, 0.f, 0.f, 0.f};
                #pragma unroll
                for (int kb = 0; kb < 4; ++kb){
                    #pragma unroll
                    for (int q = 0; q < 4; ++q)
                        acc[kb] = __builtin_amdgcn_mfma_f32_16x16x32_f16(ah[q], bh[kb][q], acc[kb], 0, 0, 0);
                    #pragma unroll
                    for (int q = 0; q < 4; ++q)
                        acc[kb] = __builtin_amdgcn_mfma_f32_16x16x32_f16(ah[q], bl[kb][q], acc[kb], 0, 0, 0);
                    #pragma unroll
                    for (int q = 0; q < 4; ++q)
                        acc[kb] = __builtin_amdgcn_mfma_f32_16x16x32_f16(al[q], bh[kb][q], acc[kb], 0, 0, 0);
                }

                // bookkeeping: rank by s = c2 - 2*dot (r2 const per row); packed sortable u32 | k
                #pragma unroll
                for (int rg = 0; rg < 4; ++rg){
                    unsigned u[4];
                    #pragma unroll
                    for (int kb = 0; kb < 4; ++kb){
                        const float sv = fmaf(-2.f, acc[kb][rg], c2r[kb]);
                        const int b = __float_as_int(sv);
                        const unsigned uu = (unsigned)(b ^ ((b >> 31) | (int)0x80000000));
                        u[kb] = (uu & 0xFFFFFC00u) | kreg[kb];
                    }
                    const unsigned m01 = umin(u[0], u[1]), M01 = umax(u[0], u[1]);
                    const unsigned m23 = umin(u[2], u[3]), M23 = umax(u[2], u[3]);
                    unsigned p1 = umin(m01, m23);
                    unsigned p2 = umin(umax(m01, m23), umin(M01, M23));
                    DPP_TOP2(p1, p2, 0x121)   // row_ror:1
                    DPP_TOP2(p1, p2, 0x122)   // row_ror:2
                    DPP_TOP2(p1, p2, 0x124)   // row_ror:4
                    DPP_TOP2(p1, p2, 0x128)   // row_ror:8
                    if (col == 0){
                        const int row = rb * 16 + ((ln >> 4) << 2) + rg;
                        mslot[row * 17 + wv * 2 + half] =
                            ((unsigned long long)p2 << 32) | (unsigned long long)p1;
                    }
                }
            }
        }
        __syncthreads();   // all unit top-2 written

        // ---- final merge: top-2 over 16 units (32 packed values) per row ----
        if (tid < BN){
            unsigned b1 = 0xFFFFFFFFu, b2 = 0xFFFFFFFFu;
            for (int i = 0; i < 16; ++i){
                const int ii = (i + tid) & 15;
                const unsigned long long v = mslot[tid * 17 + ii];
                const unsigned lo = (unsigned)v, hi = (unsigned)(v >> 32);
                if (lo < b1){ b2 = b1; b1 = lo; } else if (lo < b2) b2 = lo;
                if (hi < b1){ b2 = b1; b1 = hi; } else if (hi < b2) b2 = hi;
            }
            cand[tid][0] = (int)(b1 & 1023u);
            cand[tid][1] = (int)(b2 & 1023u);
        }
        __syncthreads();

        // ---- exact XLA-bits re-eval of both candidates (r2 + dot chains interleaved) ----
        if (tid < 2 * BN){
            const int row = tid >> 1, cd = tid & 1;
            const int k = cand[row][cd];
            const float* cw = cb + (size_t)k * W;
            float r2 = 0.f, dot = 0.f;
            for (int w = 0; w < W; ++w){
                const float rv = Rt[row][w];
                r2  = faddr(r2, fmulr(rv, rv));
                dot = __fmaf_rn(rv, cw[w], dot);
            }
            dve[row][cd] = faddr(fsubr(r2, faddr(dot, dot)), c2g[st * K + k]);
        }
        __syncthreads();

        // ---- decide (lexicographic: XLA first-min) + outputs ----
        if (tid < BN){
            const float a0 = dve[tid][0], a1 = dve[tid][1];
            const int   i0 = cand[tid][0], i1 = cand[tid][1];
            int wi; float wd;
            if (a1 < a0 || (a1 == a0 && i1 < i0)){ wi = i1; wd = a1; } else { wi = i0; wd = a0; }
            widx[tid] = wi;
            out[(size_t)st * NRW + (n0 + tid)] = (float)wi;
            out[(size_t)C * NRW + (size_t)(n0 + tid) * C + st] = __fsqrt_rn(fmaxf(wd, 0.f));
        }
        __syncthreads();

        // ---- residual -= cb[idx], elementwise f32 (bit-exact) ----
        if (st < C - 1){
            for (int e = tid; e < BN * 32; e += NT){
                const int row = e >> 5, q = e & 31;
                const float4 v = cb4[(size_t)widx[row] * 32 + q];
                float* rp = &Rt[row][q * 4];
                rp[0] = fsubr(rp[0], v.x);
                rp[1] = fsubr(rp[1], v.y);
                rp[2] = fsubr(rp[2], v.z);
                rp[3] = fsubr(rp[3], v.w);
            }
        }
    }
}

extern "C" void kernel_launch(void* const* d_in, const int* in_sizes, int n_in,
                              void* d_out, int out_size, void* d_ws, size_t ws_size,
                              hipStream_t stream) {
    const float* X  = (const float*)d_in[0];
    const float* CB = (const float*)d_in[1];
    float* out = (float*)d_out;

    float* c2g = (float*)d_ws;                              // 16 KB
    f16*   Bh  = (f16*)((char*)d_ws + 16384);               // 1 MB
    f16*   Bl  = (f16*)((char*)d_ws + 16384 + 1048576);     // 1 MB

    c2_kernel<<<dim3((C * K + 255) / 256), 256, 0, stream>>>(CB, c2g);
    split_kernel<<<dim3(C * K * 16 / 256), 256, 0, stream>>>(CB, Bh, Bl);
    rq10_kernel<<<dim3(NRW / BN), NT, 0, stream>>>(X, CB, c2g, Bh, Bl, out);
}